// Round 11
// baseline (218.935 us; speedup 1.0000x reference)
//
#include <hip/hip_runtime.h>

#define DIM 128
#define NN 72
#define BB 2
#define NSQ (NN*NN)        // 5184
#define NROWS (BB*NSQ)     // 10368
#define BN (BB*NN)         // 144
#define GRID 648           // = NROWS/16 = BB*18*18

// Grid-wide barrier — R4-proven structure, with the spin FIXED:
// poll is a RELAXED agent atomic (no per-iteration cache invalidate; atomics
// read the coherent point regardless of ordering) + s_sleep backoff. One
// acquire fence after the wait. Safe: 648 blocks, 16 KB LDS,
// launch_bounds(256,3) => >=3 blocks/CU * 256 CU = 768 co-resident slots.
__device__ __forceinline__ void grid_barrier(unsigned* cnt) {
    __syncthreads();
    if (threadIdx.x == 0) {
        __threadfence();                      // release: publish phase-1 writes
        atomicAdd(cnt, 1u);
        while (__hip_atomic_load(cnt, __ATOMIC_RELAXED,
                                 __HIP_MEMORY_SCOPE_AGENT) < (unsigned)GRID) {
            __builtin_amdgcn_s_sleep(8);
        }
    }
    __syncthreads();
    __threadfence();                          // acquire for all waves
}

__global__ __launch_bounds__(256, 3) void k_fused(
        const float* __restrict__ path, const float* __restrict__ Whz,
        const float* __restrict__ bhz,  const float* __restrict__ node,
        const float* __restrict__ Wzz,  const float* __restrict__ bzz,
        float* __restrict__ z,  float* __restrict__ zT,
        float* __restrict__ P1, float* __restrict__ P3,
        unsigned* cnt, float* __restrict__ out) {
    __shared__ float rows[16 * DIM];   // 8 KB (reused across phases)
    __shared__ float comb[16 * DIM];   // 8 KB
    const int t   = threadIdx.x;
    const int blk = blockIdx.x;

    // ---------------- phase 1: z = path@W_hz + b_hz (16 rows/block) ---------
    {
        const int r0 = blk * 16;
        {
            float4* rs = (float4*)rows;
            const float4* pg = (const float4*)(path + r0 * DIM);
            rs[t]       = pg[t];
            rs[t + 256] = pg[t + 256];
        }
        __syncthreads();

        const int e2 = t & 63;
        const int rg = t >> 6;
        float2 bz = *(const float2*)&bhz[2 * e2];
        float2 acc[4];
#pragma unroll
        for (int r = 0; r < 4; r++) acc[r] = bz;

        const float* Wp = Whz + 2 * e2;
        float2 w0[4], w1[4], n0[4], n1[4];
#pragma unroll
        for (int dd = 0; dd < 4; dd++) {
            w0[dd] = *(const float2*)&Wp[dd * DIM];
            w1[dd] = *(const float2*)&Wp[(4 + dd) * DIM];
        }
        for (int d8 = 0; d8 < 16; d8++) {
            if (d8 < 15) {
#pragma unroll
                for (int dd = 0; dd < 4; dd++) {
                    n0[dd] = *(const float2*)&Wp[(8 * d8 + 8 + dd) * DIM];
                    n1[dd] = *(const float2*)&Wp[(8 * d8 + 12 + dd) * DIM];
                }
            }
            float4 pa[4], pb[4];
#pragma unroll
            for (int r = 0; r < 4; r++) {
                pa[r] = *(const float4*)&rows[(rg + 4 * r) * DIM + 8 * d8];
                pb[r] = *(const float4*)&rows[(rg + 4 * r) * DIM + 8 * d8 + 4];
            }
#pragma unroll
            for (int dd = 0; dd < 4; dd++)
#pragma unroll
                for (int r = 0; r < 4; r++) {
                    float pv = ((const float*)&pa[r])[dd];
                    acc[r].x = fmaf(pv, w0[dd].x, acc[r].x);
                    acc[r].y = fmaf(pv, w0[dd].y, acc[r].y);
                }
#pragma unroll
            for (int dd = 0; dd < 4; dd++)
#pragma unroll
                for (int r = 0; r < 4; r++) {
                    float pv = ((const float*)&pb[r])[dd];
                    acc[r].x = fmaf(pv, w1[dd].x, acc[r].x);
                    acc[r].y = fmaf(pv, w1[dd].y, acc[r].y);
                }
#pragma unroll
            for (int dd = 0; dd < 4; dd++) { w0[dd] = n0[dd]; w1[dd] = n1[dd]; }
        }
#pragma unroll
        for (int r = 0; r < 4; r++) {
            int row = r0 + rg + 4 * r;
            *(float2*)&z[row * DIM + 2 * e2] = acc[r];
            int b  = row / NSQ;
            int ij = row - b * NSQ;
            int i  = ij / NN;
            int j  = ij - i * NN;
            *(float2*)&zT[(b * NSQ + j * NN + i) * DIM + 2 * e2] = acc[r];
        }
    }

    // ---------------- phase 1b: blocks 0..8 node GEMM (P1/P3) ---------------
    if (blk < 9) {
        __syncthreads();   // all waves done with `rows` before overwrite
        const int r0 = blk * 16;
        {
            float4* rs = (float4*)rows;
            const float4* ng = (const float4*)(node + r0 * DIM);
            rs[t]       = ng[t];
            rs[t + 256] = ng[t + 256];
        }
        __syncthreads();

        const int e2 = t & 63;
        const int rg = t >> 6;
        float2 a1[4], a3[4];
#pragma unroll
        for (int r = 0; r < 4; r++) {
            a1[r] = make_float2(0.f, 0.f);
            a3[r] = make_float2(0.f, 0.f);
        }
        const float* W1p = Wzz + 2 * e2;
        const float* W3p = Wzz + 2 * DIM * DIM + 2 * e2;
        float2 u0[4], u1[4], v0[4], v1[4];
        float2 un0[4], un1[4], vn0[4], vn1[4];
#pragma unroll
        for (int dd = 0; dd < 4; dd++) {
            u0[dd] = *(const float2*)&W1p[dd * DIM];
            u1[dd] = *(const float2*)&W1p[(4 + dd) * DIM];
            v0[dd] = *(const float2*)&W3p[dd * DIM];
            v1[dd] = *(const float2*)&W3p[(4 + dd) * DIM];
        }
        for (int d8 = 0; d8 < 16; d8++) {
            if (d8 < 15) {
#pragma unroll
                for (int dd = 0; dd < 4; dd++) {
                    un0[dd] = *(const float2*)&W1p[(8 * d8 + 8 + dd) * DIM];
                    un1[dd] = *(const float2*)&W1p[(8 * d8 + 12 + dd) * DIM];
                    vn0[dd] = *(const float2*)&W3p[(8 * d8 + 8 + dd) * DIM];
                    vn1[dd] = *(const float2*)&W3p[(8 * d8 + 12 + dd) * DIM];
                }
            }
            float4 pa[4], pb[4];
#pragma unroll
            for (int r = 0; r < 4; r++) {
                pa[r] = *(const float4*)&rows[(rg + 4 * r) * DIM + 8 * d8];
                pb[r] = *(const float4*)&rows[(rg + 4 * r) * DIM + 8 * d8 + 4];
            }
#pragma unroll
            for (int dd = 0; dd < 4; dd++)
#pragma unroll
                for (int r = 0; r < 4; r++) {
                    float pv = ((const float*)&pa[r])[dd];
                    a1[r].x = fmaf(pv, u0[dd].x, a1[r].x);
                    a1[r].y = fmaf(pv, u0[dd].y, a1[r].y);
                    a3[r].x = fmaf(pv, v0[dd].x, a3[r].x);
                    a3[r].y = fmaf(pv, v0[dd].y, a3[r].y);
                }
#pragma unroll
            for (int dd = 0; dd < 4; dd++)
#pragma unroll
                for (int r = 0; r < 4; r++) {
                    float pv = ((const float*)&pb[r])[dd];
                    a1[r].x = fmaf(pv, u1[dd].x, a1[r].x);
                    a1[r].y = fmaf(pv, u1[dd].y, a1[r].y);
                    a3[r].x = fmaf(pv, v1[dd].x, a3[r].x);
                    a3[r].y = fmaf(pv, v1[dd].y, a3[r].y);
                }
#pragma unroll
            for (int dd = 0; dd < 4; dd++) {
                u0[dd] = un0[dd]; u1[dd] = un1[dd];
                v0[dd] = vn0[dd]; v1[dd] = vn1[dd];
            }
        }
#pragma unroll
        for (int r = 0; r < 4; r++) {
            int m = r0 + rg + 4 * r;
            *(float2*)&P1[m * DIM + 2 * e2] = a1[r];
            *(float2*)&P3[m * DIM + 2 * e2] = a3[r];
        }
    }

    grid_barrier(cnt);

    // ---------------- phase 2: tropical conv, 4x4 (i,j) tile ----------------
    const int b   = blk / 324;
    const int rem = blk - b * 324;
    const int it  = rem / 18;
    const int jt  = rem - it * 18;
    const int i0 = it * 4, j0 = jt * 4;
    const int d  = t & 127;
    const int ty = t >> 7;    // k parity
    const float* zb  = z  + b * NSQ * DIM;
    const float* zTb = zT + b * NSQ * DIM;
    {
        float acc[16];
#pragma unroll
        for (int q = 0; q < 16; q++) acc[q] = -3.402823466e38f;

        float cur[32], nxt[32];   // [kk*8 + s]: s=0..3 zi, 4..7 zj
#pragma unroll
        for (int kk = 0; kk < 4; kk++) {
            int k = ty + 2 * kk;
#pragma unroll
            for (int s = 0; s < 4; s++) {
                cur[kk * 8 + s]     = zb [((i0 + s) * NN + k) * DIM + d];
                cur[kk * 8 + 4 + s] = zTb[((j0 + s) * NN + k) * DIM + d];
            }
        }
        for (int g = 0; g < 9; g++) {
            if (g < 8) {
#pragma unroll
                for (int kk = 0; kk < 4; kk++) {
                    int k = ty + 2 * kk + 8 * (g + 1);
#pragma unroll
                    for (int s = 0; s < 4; s++) {
                        nxt[kk * 8 + s]     = zb [((i0 + s) * NN + k) * DIM + d];
                        nxt[kk * 8 + 4 + s] = zTb[((j0 + s) * NN + k) * DIM + d];
                    }
                }
            }
#pragma unroll
            for (int kk = 0; kk < 4; kk++)
#pragma unroll
                for (int a = 0; a < 4; a++)
#pragma unroll
                    for (int c = 0; c < 4; c++)
                        acc[a * 4 + c] = fmaxf(acc[a * 4 + c],
                                               cur[kk * 8 + a] + cur[kk * 8 + 4 + c]);
#pragma unroll
            for (int q = 0; q < 32; q++) cur[q] = nxt[q];
        }

        if (ty == 1) {
#pragma unroll
            for (int q = 0; q < 16; q++) comb[q * DIM + d] = acc[q];
        }
        __syncthreads();
        if (ty == 0) {
#pragma unroll
            for (int a = 0; a < 4; a++)
#pragma unroll
                for (int c = 0; c < 4; c++) {
                    int q = a * 4 + c;
                    float m = fmaxf(acc[q], comb[q * DIM + d]);
                    int idx = ((i0 + a) * NN + (j0 + c)) * DIM + d;
                    rows[q * DIM + d] = fmaxf(m, zb[idx]);
                }
        }
    }
    __syncthreads();

    // ---------------- phase 3: out = relu(zmax@W2 + P1 + P3 + b) ------------
    {
        const int e2 = t & 63;
        const int rg = t >> 6;
        float2 acc[4];
#pragma unroll
        for (int r = 0; r < 4; r++) acc[r] = make_float2(0.f, 0.f);

        const float* Wp = Wzz + DIM * DIM + 2 * e2;   // W2 block
        float2 w0[4], w1[4], n0[4], n1[4];
#pragma unroll
        for (int dd = 0; dd < 4; dd++) {
            w0[dd] = *(const float2*)&Wp[dd * DIM];
            w1[dd] = *(const float2*)&Wp[(4 + dd) * DIM];
        }
        for (int d8 = 0; d8 < 16; d8++) {
            if (d8 < 15) {
#pragma unroll
                for (int dd = 0; dd < 4; dd++) {
                    n0[dd] = *(const float2*)&Wp[(8 * d8 + 8 + dd) * DIM];
                    n1[dd] = *(const float2*)&Wp[(8 * d8 + 12 + dd) * DIM];
                }
            }
            float4 pa[4], pb[4];
#pragma unroll
            for (int r = 0; r < 4; r++) {
                pa[r] = *(const float4*)&rows[(rg + 4 * r) * DIM + 8 * d8];
                pb[r] = *(const float4*)&rows[(rg + 4 * r) * DIM + 8 * d8 + 4];
            }
#pragma unroll
            for (int dd = 0; dd < 4; dd++)
#pragma unroll
                for (int r = 0; r < 4; r++) {
                    float pv = ((const float*)&pa[r])[dd];
                    acc[r].x = fmaf(pv, w0[dd].x, acc[r].x);
                    acc[r].y = fmaf(pv, w0[dd].y, acc[r].y);
                }
#pragma unroll
            for (int dd = 0; dd < 4; dd++)
#pragma unroll
                for (int r = 0; r < 4; r++) {
                    float pv = ((const float*)&pb[r])[dd];
                    acc[r].x = fmaf(pv, w1[dd].x, acc[r].x);
                    acc[r].y = fmaf(pv, w1[dd].y, acc[r].y);
                }
#pragma unroll
            for (int dd = 0; dd < 4; dd++) { w0[dd] = n0[dd]; w1[dd] = n1[dd]; }
        }

        float2 bz = *(const float2*)&bzz[2 * e2];
#pragma unroll
        for (int r = 0; r < 4; r++) {
            int q = rg + 4 * r;        // LDS row index = a*4+c
            int a = q >> 2, c = q & 3;
            int orow = b * NSQ + (i0 + a) * NN + (j0 + c);
            float2 v1 = *(const float2*)&P1[(b * NN + i0 + a) * DIM + 2 * e2];
            float2 v3 = *(const float2*)&P3[(b * NN + j0 + c) * DIM + 2 * e2];
            float ox = fmaxf(acc[r].x + v1.x + v3.x + bz.x, 0.f);
            float oy = fmaxf(acc[r].y + v1.y + v3.y + bz.y, 0.f);
            *(float2*)&out[orow * DIM + 2 * e2] = make_float2(ox, oy);
        }
    }
}

extern "C" void kernel_launch(void* const* d_in, const int* in_sizes, int n_in,
                              void* d_out, int out_size, void* d_ws, size_t ws_size,
                              hipStream_t stream) {
    const float* node = (const float*)d_in[0];
    const float* path = (const float*)d_in[1];
    const float* Whz  = (const float*)d_in[2];
    const float* bhz  = (const float*)d_in[3];
    const float* Wzz  = (const float*)d_in[4];
    const float* bzz  = (const float*)d_in[5];
    float* out = (float*)d_out;

    unsigned* cnt = (unsigned*)d_ws;        // barrier counter (zeroed below)
    float* base = (float*)d_ws;
    float* z  = base + 256;                 // 1 KB offset keeps z 16B-aligned
    float* zT = z  + NROWS * DIM;
    float* P1 = zT + NROWS * DIM;
    float* P3 = P1 + BN * DIM;

    hipMemsetAsync(d_ws, 0, 64, stream);    // zero barrier counter (graph node)
    hipLaunchKernelGGL(k_fused, dim3(GRID), dim3(256), 0, stream,
                       path, Whz, bhz, node, Wzz, bzz, z, zT, P1, P3, cnt, out);
}